// Round 8
// baseline (265.339 us; speedup 1.0000x reference)
//
#include <hip/hip_runtime.h>

#define DFEAT 64
#define NG 64
#define TILE 128        // nodes per bucket/tile (bucket = tgt >> 7)
#define NBLK 256        // binning blocks (must equal blockDim of k_colscan)
#define NBMAX 1024      // max buckets supported in LDS

// ---------------- pass A: per-block-chunk bucket histogram -> cnt_m[blk][b] -----
__global__ __launch_bounds__(256) void k_cnt(const int* __restrict__ col,
                                             int* __restrict__ cnt_m,
                                             int e, int nb, int chunk) {
  __shared__ int hist[NBMAX];
  int tid = threadIdx.x;
  int blk = blockIdx.x;
  for (int b = tid; b < nb; b += 256) hist[b] = 0;
  __syncthreads();
  int lo = blk * chunk, hi = min(lo + chunk, e);
  for (int i = lo + tid; i < hi; i += 256)
    atomicAdd(&hist[col[i] >> 7], 1);
  __syncthreads();
  for (int b = tid; b < nb; b += 256)
    cnt_m[(size_t)blk * nb + b] = hist[b];
}

// ---------------- pass B: per-bucket scan over blocks (in place) + totals -------
__global__ __launch_bounds__(256) void k_colscan(int* __restrict__ cnt_m,
                                                 int* __restrict__ gcount, int nb) {
  __shared__ int sh[256];
  int tid = threadIdx.x;
  int b = blockIdx.x;
  int v = cnt_m[(size_t)tid * nb + b];
  sh[tid] = v;
  __syncthreads();
  for (int off = 1; off < 256; off <<= 1) {
    int t = (tid >= off) ? sh[tid - off] : 0;
    __syncthreads();
    sh[tid] += t;
    __syncthreads();
  }
  cnt_m[(size_t)tid * nb + b] = sh[tid] - v;  // exclusive over blocks
  if (tid == 255) gcount[b] = sh[255];
}

// ---------------- scan bucket totals -> base[0..nb] ----------------------------
__global__ __launch_bounds__(1024) void k_bscan(const int* __restrict__ gcount,
                                                int* __restrict__ base, int nb) {
  __shared__ int sh[1024];
  int tid = threadIdx.x;
  int v = (tid < nb) ? gcount[tid] : 0;
  sh[tid] = v;
  __syncthreads();
  for (int off = 1; off < 1024; off <<= 1) {
    int t = (tid >= off) ? sh[tid - off] : 0;
    __syncthreads();
    sh[tid] += t;
    __syncthreads();
  }
  if (tid < nb) base[tid] = sh[tid] - v;
  if (tid == 0) base[nb] = sh[1023];
}

// ---------------- pass C: place edges, LDS cursors only, packed payload --------
// pairs[pos] = src | ((tgt & 127) << 20)   (requires n < 2^20)
__global__ __launch_bounds__(256) void k_bin2(const int* __restrict__ row,
                                              const int* __restrict__ col,
                                              const int* __restrict__ base,
                                              const int* __restrict__ cnt_m,
                                              int* __restrict__ pairs,
                                              int e, int nb, int chunk) {
  __shared__ int gl[NBMAX];
  __shared__ int lcur[NBMAX];
  int tid = threadIdx.x;
  int blk = blockIdx.x;
  for (int b = tid; b < nb; b += 256) {
    gl[b] = base[b] + cnt_m[(size_t)blk * nb + b];
    lcur[b] = 0;
  }
  __syncthreads();
  int lo = blk * chunk, hi = min(lo + chunk, e);
  for (int i = lo + tid; i < hi; i += 256) {
    int s = row[i], t = col[i];
    int b = t >> 7;
    int pos = gl[b] + atomicAdd(&lcur[b], 1);
    pairs[pos] = s | ((t & (TILE - 1)) << 20);
  }
}

// ---------------- per-tile CSR: node-ordered srcs, starts[], dinv ---------------
__global__ __launch_bounds__(256) void k_csr(const int* __restrict__ pairs,
                                             const int* __restrict__ base,
                                             int* __restrict__ starts,
                                             int* __restrict__ srcs,
                                             float* __restrict__ dinv,
                                             int n, int e) {
  __shared__ int cnt[TILE];
  __shared__ int cur[TILE];
  __shared__ int sc[TILE];
  int tid = threadIdx.x;
  int b = blockIdx.x;
  int tile0 = b * TILE;
  if (tid < TILE) cnt[tid] = 0;
  __syncthreads();
  int e0 = base[b], e1 = base[b + 1];
  for (int i = e0 + tid; i < e1; i += 256)
    atomicAdd(&cnt[(unsigned)pairs[i] >> 20], 1);
  __syncthreads();
  int c = (tid < TILE) ? cnt[tid] : 0;
  if (tid < TILE) sc[tid] = c;
  __syncthreads();
  for (int off = 1; off < TILE; off <<= 1) {
    int t = (tid < TILE && tid >= off) ? sc[tid - off] : 0;
    __syncthreads();
    if (tid < TILE) sc[tid] += t;
    __syncthreads();
  }
  if (tid < TILE) {
    int excl = sc[tid] - c;
    cur[tid] = excl;
    int node = tile0 + tid;
    if (node < n) {
      starts[node] = e0 + excl;
      dinv[node] = rsqrtf(1.0f + (float)c);
    }
  }
  if (b == 0 && tid == 0) starts[n] = e;
  __syncthreads();
  for (int i = e0 + tid; i < e1; i += 256) {
    int p = pairs[i];
    int pos = atomicAdd(&cur[(unsigned)p >> 20], 1);
    srcs[e0 + pos] = p & 0xFFFFF;
  }
}

// ---------------- u = A_hat * 1 : u[c] = dinv[c]*(dinv[c] + sum dinv[src]) ------
__global__ void k_u(const int* __restrict__ starts, const int* __restrict__ srcs,
                    const float* __restrict__ dinv, float* __restrict__ u, int n) {
  int i = blockIdx.x * 256 + threadIdx.x;
  if (i >= n) return;
  int s = starts[i], e1 = starts[i + 1];
  float d = dinv[i];
  float acc = d;
  for (int j = s; j < e1; ++j) acc += dinv[srcs[j]];
  u[i] = d * acc;
}

// ---------------- WW = W1@W2 (64x64), bw = b1^T @ W2 ----------------------------
__global__ __launch_bounds__(256) void k_w12(const float* __restrict__ W1,
                                             const float* __restrict__ W2,
                                             const float* __restrict__ b1,
                                             float* __restrict__ WW,
                                             float* __restrict__ bw) {
  __shared__ float w1[4096], w2[4096];
  int tid = threadIdx.x;
  for (int i = tid; i < 4096; i += 256) { w1[i] = W1[i]; w2[i] = W2[i]; }
  __syncthreads();
  for (int p = tid; p < 4096; p += 256) {
    int k = p >> 6, d = p & 63;
    float a = 0.f;
    for (int m = 0; m < 64; ++m) a += w1[k * 64 + m] * w2[m * 64 + d];
    WW[p] = a;
  }
  if (tid < 64) {
    float a = 0.f;
    for (int k = 0; k < 64; ++k) a += b1[k] * w2[k * 64 + tid];
    bw[tid] = a;
  }
}

// ---------------- gather: o = A_hat * h, ONE NODE PER WAVE ----------------------
// 16 lanes per source row (float4 each = full 256 B row), 4 row-slots (qr),
// unroll x4 -> 16 rows (4 KB) outstanding per wave. shfl_xor reduce over qr.
__global__ __launch_bounds__(256) void k_gather(const int* __restrict__ starts,
                                                const int* __restrict__ srcs,
                                                const float* __restrict__ dinv,
                                                const float* __restrict__ h,
                                                float* __restrict__ o, int n) {
  int node = blockIdx.x * 4 + (threadIdx.x >> 6);
  if (node >= n) return;
  int lane = threadIdx.x & 63;
  int qr = lane >> 4;      // row slot 0..3
  int f4 = (lane & 15) * 4;  // feature quarter
  int s = starts[node];
  int deg = starts[node + 1] - s;
  float dc = dinv[node];
  float4 acc = {0.f, 0.f, 0.f, 0.f};
  int j = 0;
  for (; j + 16 <= deg; j += 16) {
    int r0 = srcs[s + j + qr];
    int r1 = srcs[s + j + 4 + qr];
    int r2 = srcs[s + j + 8 + qr];
    int r3 = srcs[s + j + 12 + qr];
    float w0 = dinv[r0], w1 = dinv[r1], w2 = dinv[r2], w3 = dinv[r3];
    float4 v0 = *(const float4*)(&h[(size_t)r0 * 64 + f4]);
    float4 v1 = *(const float4*)(&h[(size_t)r1 * 64 + f4]);
    float4 v2 = *(const float4*)(&h[(size_t)r2 * 64 + f4]);
    float4 v3 = *(const float4*)(&h[(size_t)r3 * 64 + f4]);
    acc.x += w0 * v0.x + w1 * v1.x + w2 * v2.x + w3 * v3.x;
    acc.y += w0 * v0.y + w1 * v1.y + w2 * v2.y + w3 * v3.y;
    acc.z += w0 * v0.z + w1 * v1.z + w2 * v2.z + w3 * v3.z;
    acc.w += w0 * v0.w + w1 * v1.w + w2 * v2.w + w3 * v3.w;
  }
  for (; j + 4 <= deg; j += 4) {
    int r = srcs[s + j + qr];
    float w = dinv[r];
    float4 v = *(const float4*)(&h[(size_t)r * 64 + f4]);
    acc.x += w * v.x; acc.y += w * v.y; acc.z += w * v.z; acc.w += w * v.w;
  }
  int rem = deg - j;
  if (qr < rem) {
    int r = srcs[s + j + qr];
    float w = dinv[r];
    float4 v = *(const float4*)(&h[(size_t)r * 64 + f4]);
    acc.x += w * v.x; acc.y += w * v.y; acc.z += w * v.z; acc.w += w * v.w;
  }
  // reduce over the 4 row-slot groups (lane bits 4 and 5)
  acc.x += __shfl_xor(acc.x, 16); acc.y += __shfl_xor(acc.y, 16);
  acc.z += __shfl_xor(acc.z, 16); acc.w += __shfl_xor(acc.w, 16);
  acc.x += __shfl_xor(acc.x, 32); acc.y += __shfl_xor(acc.y, 32);
  acc.z += __shfl_xor(acc.z, 32); acc.w += __shfl_xor(acc.w, 32);
  if (qr == 0) {
    float4 hs = *(const float4*)(&h[(size_t)node * 64 + f4]);
    float4 res;
    res.x = dc * dc * hs.x + dc * acc.x;
    res.y = dc * dc * hs.y + dc * acc.y;
    res.z = dc * dc * hs.z + dc * acc.z;
    res.w = dc * dc * hs.w + dc * acc.w;
    *(float4*)(&o[(size_t)node * 64 + f4]) = res;
  }
}

// ---------------- pool z2 rows, u, and counts (batch sorted) --------------------
__global__ void k_pool2(const float* __restrict__ z2, const float* __restrict__ u,
                        const int* __restrict__ batch, float* __restrict__ S,
                        float* __restrict__ T, float* __restrict__ cntf, int n) {
  int d = threadIdx.x;
  int start = blockIdx.x * 64;
  if (start >= n) return;
  int end = min(start + 64, n);
  int curg = batch[start];
  float acc = 0.f, cnt = 0.f, ua = 0.f;
  for (int i = start; i < end; ++i) {
    int g = batch[i];
    if (g != curg) {
      unsafeAtomicAdd(&S[curg * 64 + d], acc);
      if (d == 0) {
        unsafeAtomicAdd(&cntf[curg], cnt);
        unsafeAtomicAdd(&T[curg], ua);
      }
      acc = 0.f; cnt = 0.f; ua = 0.f;
      curg = g;
    }
    acc += z2[(size_t)i * 64 + d];
    if (d == 0) { cnt += 1.f; ua += u[i]; }
  }
  unsafeAtomicAdd(&S[curg * 64 + d], acc);
  if (d == 0) {
    unsafeAtomicAdd(&cntf[curg], cnt);
    unsafeAtomicAdd(&T[curg], ua);
  }
}

// ---------------- final: out[g] = (S[g]@WW + T[g]*bw)/cnt + b2 ------------------
__global__ __launch_bounds__(256) void k_final2(const float* __restrict__ S,
                                                const float* __restrict__ T,
                                                const float* __restrict__ cntf,
                                                const float* __restrict__ WW,
                                                const float* __restrict__ bw,
                                                const float* __restrict__ b2,
                                                float* __restrict__ out) {
  __shared__ float sS[4096], sW[4096];
  int tid = threadIdx.x;
  for (int i = tid; i < 4096; i += 256) { sS[i] = S[i]; sW[i] = WW[i]; }
  __syncthreads();
  for (int p = tid; p < 4096; p += 256) {
    int g = p >> 6, d = p & 63;
    float a = 0.f;
    for (int k = 0; k < 64; ++k) a += sS[g * 64 + k] * sW[k * 64 + d];
    float c = fmaxf(cntf[g], 1.0f);
    out[p] = (a + T[g] * bw[d]) / c + b2[d];
  }
}

extern "C" void kernel_launch(void* const* d_in, const int* in_sizes, int n_in,
                              void* d_out, int out_size, void* d_ws, size_t ws_size,
                              hipStream_t stream) {
  const float* x = (const float*)d_in[0];
  const int* ei = (const int*)d_in[1];
  const int* bat = (const int*)d_in[2];
  const float* W1 = (const float*)d_in[3];
  const float* b1 = (const float*)d_in[4];
  const float* W2 = (const float*)d_in[5];
  const float* b2 = (const float*)d_in[6];
  float* out = (float*)d_out;

  int n = in_sizes[0] / 64;  // 100000
  int e = in_sizes[1] / 2;   // 1000000
  const int* rowp = ei;      // sources
  const int* colp = ei + e;  // targets
  int nb = (n + TILE - 1) / TILE;      // 782 buckets (< NBMAX)
  int chunk = (e + NBLK - 1) / NBLK;   // edges per binning block

  // workspace: [S][cntf][T] (zeroed) | gcount, base, cnt_m, dinv, starts, srcs,
  // u, WW, bw, z1 (packed pairs alias z1), z2.  Total ~57 MB.
  char* ws = (char*)d_ws;
  size_t off = 0;
  auto alloc = [&](size_t elems) {
    void* p = ws + off;
    off += ((elems * 4 + 255) & ~(size_t)255);
    return p;
  };
  float* S = (float*)alloc(NG * DFEAT);
  float* cntf = (float*)alloc(NG);
  float* T = (float*)alloc(NG);
  size_t zbytes = off;
  int* gcount = (int*)alloc(nb);
  int* base = (int*)alloc(nb + 1);
  int* cnt_m = (int*)alloc((size_t)NBLK * nb);
  float* dinv = (float*)alloc(n);
  int* starts = (int*)alloc(n + 1);
  int* srcs = (int*)alloc(e);
  float* u = (float*)alloc(n);
  float* WW = (float*)alloc(DFEAT * DFEAT);
  float* bw = (float*)alloc(DFEAT);
  float* z1 = (float*)alloc((size_t)n * 64);
  float* z2 = (float*)alloc((size_t)n * 64);
  int* pairs = (int*)z1;  // dead after k_csr; z1 first written after that

  int nbn = (n + 255) / 256;
  int nbw = (n + 3) / 4;  // gather: 1 node per wave, 4 waves per block

  hipMemsetAsync(S, 0, zbytes, stream);
  k_cnt<<<NBLK, 256, 0, stream>>>(colp, cnt_m, e, nb, chunk);
  k_colscan<<<nb, 256, 0, stream>>>(cnt_m, gcount, nb);
  k_bscan<<<1, 1024, 0, stream>>>(gcount, base, nb);
  k_bin2<<<NBLK, 256, 0, stream>>>(rowp, colp, base, cnt_m, pairs, e, nb, chunk);
  k_csr<<<nb, 256, 0, stream>>>(pairs, base, starts, srcs, dinv, n, e);
  k_u<<<nbn, 256, 0, stream>>>(starts, srcs, dinv, u, n);
  k_w12<<<1, 256, 0, stream>>>(W1, W2, b1, WW, bw);

  // z1 = A_hat * x ; z2 = A_hat * z1
  k_gather<<<nbw, 256, 0, stream>>>(starts, srcs, dinv, x, z1, n);
  k_gather<<<nbw, 256, 0, stream>>>(starts, srcs, dinv, z1, z2, n);

  // pool + tiny final matmul
  k_pool2<<<(n + 63) / 64, 64, 0, stream>>>(z2, u, bat, S, T, cntf, n);
  k_final2<<<1, 256, 0, stream>>>(S, T, cntf, WW, bw, b2, out);
}